// Round 13
// baseline (236.365 us; speedup 1.0000x reference)
//
#include <hip/hip_runtime.h>

// CausalSelfAttention: x[4,2048,1024] fp32 -> out fp32
// Pipeline (all bf16 MFMA, fp32 accum):
//  1) prep: cvt x->bf16 AND transpose+cvt W_attn/W_proj, ONE merged launch
//  2) gemm_cv<4,0> (128x256, BK=32, MERGED 2-barrier/K-tile counted-vmcnt,
//     768 blocks) -> Q (pre-scaled 0.125*log2e), K, V^T [b,h,d,s]
//  3) flash attention, in-register softmax (R12, unchanged: swapped QK^T +
//     key<->row map; P never touches LDS; 77 -> <71us)
//  4) gemm_cv<2,1> (128x128, grid 512 = 2x256 uniform) + bias -> out fp32
//     (ports proj from the 491 TF R0 structure onto the 715 TF template)
//
// R13 analysis (R12 = 232.8us; gemm8p 72.3us now dominant, MfmaUtil 28%,
// conflicts 0, HBM 16%):
//   Per-CU budget: MFMA ~25us floor, LDS-reads ~23us -> at 72us the pipes
//   overlap poorly: 2-phase loop = 4 barriers/K-tile, reads split across
//   phases. MERGED SCHEDULE (2 barriers/K-tile):
//     { RD all 8 A + NF B frags (max ds_read ILP);
//       ISSUE A1(t+1) + B0..B{NF-1}(t+1)   [other parity, safe];
//       MFMA half (consumes ALL af);
//       BAR                                 [retires all waves' A reads];
//       ISSUE A0(t+2)                       [same parity, now safe];
//       MFMA half;
//       vmcnt(1); BAR }                     [t+1 complete, A0(t+2) flying]
//   Outstanding: 1 -> +(NF+1) -> +1 = NF+3; vmcnt(1) drains NF+2 = tile
//   t+1 exactly. Same counted-vmcnt invariant as the proven 4-barrier
//   schedule; overwrite safety identical (B/A1 other-parity; A0(t+2)
//   after the mid-barrier). Tail: clamped dummy reloads (identical bytes).
//   launch_bounds(256,2): reg cap 256 >= ~110 used (R5 spill lesson).
// Rotation swizzle (conflict-free, verified R3): writer thread t loads
//   global chunk ((t&3)-((t>>3)&3))&3 into slot t&3; reader slot
//   (quad+(l15>>1))&3.
// MFMA 16x16x32 bf16 layouts (HW-verified per guide):
//   A: a[j] = A[m=lane&15][k=quad*8+j]  (quad=lane>>4)
//   B: b[j] = B[k=quad*8+j][n=lane&15]
//   C/D: c[i] = D[row=quad*4+i][col=lane&15]

#define BATCH 4
#define SEQ   2048
#define EMB   1024
#define NH    16
#define HD    64

typedef __bf16 bf16;
typedef __bf16 bf16x8 __attribute__((ext_vector_type(8)));
typedef __bf16 bf16x4 __attribute__((ext_vector_type(4)));
typedef float  f32x4  __attribute__((ext_vector_type(4)));

// direct global->LDS 16B copy: LDS dest is wave-uniform base + lane*16
__device__ __forceinline__ void ld_lds16(const void* g, void* l) {
  __builtin_amdgcn_global_load_lds(
      (const __attribute__((address_space(1))) void*)g,
      (__attribute__((address_space(3))) void*)l, 16, 0, 0);
}

// ---------------- prep: cvt x -> bf16  +  transpose/cvt both weights -------
// grid = 8192 (cvt) + 4096 (transpose, 128x32) = 12288 blocks x 256 thr.
__global__ void prep(const float* __restrict__ x, bf16* __restrict__ xb, int n,
                     const float* __restrict__ Wa, const float* __restrict__ Wp,
                     bf16* __restrict__ WaT, bf16* __restrict__ WpT) {
  __shared__ float tile[32][33];
  int bid = blockIdx.x;
  if (bid < 8192) {
    int i = (bid * 256 + threadIdx.x) * 4;
    if (i + 3 < n) {
      float4 v = *(const float4*)(x + i);
      bf16 o0 = (bf16)v.x, o1 = (bf16)v.y, o2 = (bf16)v.z, o3 = (bf16)v.w;
      xb[i] = o0; xb[i+1] = o1; xb[i+2] = o2; xb[i+3] = o3;
    }
    return;
  }
  int tb = bid - 8192;
  int bx = tb & 127;            // [0,128): n0-block
  int byk = tb >> 7;            // [0,32):  k0-block
  const float* W; bf16* WT; int N;
  if (bx < 96) { W = Wa; WT = WaT; N = 3072; }
  else         { W = Wp; WT = WpT; N = 1024; bx -= 96; }
  int n0 = bx * 32, k0 = byk * 32;
  int tx = threadIdx.x & 31, ty = threadIdx.x >> 5;
#pragma unroll
  for (int r = 0; r < 4; r++) {
    int k = k0 + ty + r * 8;
    tile[ty + r * 8][tx] = W[(long)k * N + n0 + tx];
  }
  __syncthreads();
#pragma unroll
  for (int r = 0; r < 4; r++) {
    int nn = n0 + ty + r * 8;
    WT[(long)nn * EMB + k0 + tx] = (bf16)tile[tx][ty + r * 8];
  }
}

#define QSCALE 0.18033688f   // (1/8) * log2(e)

// ---------------- 128x(64*NF) counted-vmcnt GEMM, merged 2-barrier loop ----
// A[M][1024] bf16 x Bt[N][1024] bf16 + bias.
// MODE 0 (NF=4, grid 768): QKV split epilogue. MODE 1 (NF=2, grid 512): f32.
template <int NF, int MODE>
__global__ __launch_bounds__(256, 2) void gemm_cv(
    const bf16* __restrict__ A, const bf16* __restrict__ Bt,
    const float* __restrict__ bias,
    bf16* __restrict__ q, bf16* __restrict__ k, bf16* __restrict__ v,
    float* __restrict__ out)
{
  constexpr int BN = NF * 64;
  constexpr int WN = NF * 16;        // per-wave col extent
  constexpr int BELEM = BN * 32;     // B elems per buffer
  __shared__ __align__(16) bf16 lds[8192 + 2 * BELEM];  // NF=4:48KB NF=2:32KB
  int lin = blockIdx.x;
  int xcd = lin & 7, s = lin >> 3;
  int by = xcd * 8 + (s & 7);        // 64 row-blocks, XCD-affine
  int bx = s >> 3;                   // col-blocks (12 or 8)
  int m0 = by * 128, n0 = bx * BN;
  int t = threadIdx.x;
  int wid = t >> 6, lane = t & 63;
  int l15 = lane & 15, quad = lane >> 4;
  int wc = wid;                      // wave: all 128 rows x cols wc*WN..

  const bf16* Ag = A + (long)m0 * EMB;
  const bf16* Bg = Bt + (long)n0 * EMB;

  f32x4 acc[8][NF] = {};
  bf16x8 af[8], bfr[NF];
  constexpr int NT = EMB / 32;       // 32 K-tiles
  // physical chunk slot for all frag reads (rotation swizzle; see header)
  int ph8 = ((quad + (l15 >> 1)) & 3) * 8;

#define LDSA(b) (lds + (b) * 4096)
#define LDSB(b) (lds + 8192 + (b) * BELEM)

  // stage a 64-row x 32-col quarter: 1 gload_lds per thread (4KB).
  // LDS dest linear; slot p=t&3 receives logical chunk (p-(r>>1))&3.
#define ISSUE64(gbase, rowoff, ldst, ktt)                                      \
  { int r_ = (rowoff) + (t >> 2);                                              \
    int g_ = ((t & 3) - ((t >> 3) & 3)) & 3;                                   \
    ld_lds16(&(gbase)[(long)r_ * EMB + (ktt) + g_ * 8],                        \
             (ldst) + ((rowoff) + wid * 16) * 32); }

#define RD_A(mi) { int r_ = (mi) * 16 + l15;                                   \
    af[mi] = *(const bf16x8*)&Ab[r_ * 32 + ph8]; }
#define RD_B(ni) { int r_ = wc * WN + (ni) * 16 + l15;                         \
    bfr[ni] = *(const bf16x8*)&Bb[r_ * 32 + ph8]; }

#define FENCE asm volatile("" ::: "memory")
#define BAR   { FENCE; __builtin_amdgcn_s_barrier(); FENCE; }

#define MFMAH(nlo, nhi)                                                        \
  { __builtin_amdgcn_s_setprio(1);                                             \
    _Pragma("unroll") for (int mi_ = 0; mi_ < 8; ++mi_)                        \
      _Pragma("unroll") for (int nj_ = (nlo); nj_ < (nhi); ++nj_)              \
        acc[mi_][nj_] = __builtin_amdgcn_mfma_f32_16x16x32_bf16(               \
            af[mi_], bfr[nj_], acc[mi_][nj_], 0, 0, 0);                        \
    __builtin_amdgcn_s_setprio(0); }

  // prologue: tile0 complete (NF+2 issues) + A0(tile1) in flight
  ISSUE64(Ag, 0,  LDSA(0), 0);
  ISSUE64(Ag, 64, LDSA(0), 0);
#pragma unroll
  for (int u = 0; u < NF; ++u) ISSUE64(Bg, u * 64, LDSB(0), 0);
  ISSUE64(Ag, 0, LDSA(1), 32);
  asm volatile("s_waitcnt vmcnt(1)" ::: "memory");
  BAR;

#pragma unroll 2
  for (int tt = 0; tt < NT; ++tt) {
    const bf16* Ab = LDSA(tt & 1);
    const bf16* Bb = LDSB(tt & 1);
    bf16* An = LDSA((tt + 1) & 1);
    bf16* Bn = LDSB((tt + 1) & 1);
    bf16* Ac = LDSA(tt & 1);                         // A0(t+2): (tt+2)&1==tt&1
    int kn  = (tt + 1 < NT ? tt + 1 : NT - 1) * 32;  // clamped at tail:
    int kn2 = (tt + 2 < NT ? tt + 2 : NT - 1) * 32;  // dummy identical reload

    // all fragment reads up front (max ds_read ILP)
#pragma unroll
    for (int mi = 0; mi < 8; ++mi) RD_A(mi);
#pragma unroll
    for (int ni = 0; ni < NF; ++ni) RD_B(ni);
    // prefetch t+1 (other-parity buffers: safe, reads finished at t-1)
    ISSUE64(Ag, 64, An, kn);
#pragma unroll
    for (int u = 0; u < NF; ++u) ISSUE64(Bg, u * 64, Bn, kn);
    // first MFMA half consumes ALL af (A reads retire before the barrier)
    MFMAH(0, NF / 2);
    BAR;                              // all waves' A reads of buf[tt&1] done
    ISSUE64(Ag, 0, Ac, kn2);          // A0(t+2) -> same-parity A buffer
    MFMAH(NF / 2, NF);
    asm volatile("s_waitcnt vmcnt(1)" ::: "memory");  // t+1 fully landed
    BAR;
  }

  asm volatile("s_waitcnt vmcnt(0)" ::: "memory");   // drain clamped DMAs
  __syncthreads();

  // ---------------- epilogue ----------------
  if (MODE == 1) {
#pragma unroll
    for (int mi = 0; mi < 8; ++mi)
#pragma unroll
      for (int ni = 0; ni < NF; ++ni) {
        int gcol = n0 + wc * WN + ni * 16 + l15;
        float bv = bias[gcol];
#pragma unroll
        for (int i = 0; i < 4; ++i) {
          int grow = m0 + mi * 16 + quad * 4 + i;
          out[(long)grow * EMB + gcol] = acc[mi][ni][i] + bv;
        }
      }
  } else {
    int which = bx >> 2;   // BN=256: tile lies entirely in Q, K, or V
    if (which < 2) {
      bf16* dst = (which == 0) ? q : k;
      float scale = (which == 0) ? QSCALE : 1.0f;
#pragma unroll
      for (int mi = 0; mi < 8; ++mi)
#pragma unroll
        for (int ni = 0; ni < NF; ++ni) {
          int gcol = n0 + wc * WN + ni * 16 + l15;
          float bv = bias[gcol];
          int e = gcol & 1023, h = e >> 6, d = e & 63;
#pragma unroll
          for (int i = 0; i < 4; ++i) {
            int grow = m0 + mi * 16 + quad * 4 + i;
            int b = grow >> 11, ss = grow & 2047;
            dst[(((long)b * NH + h) * SEQ + ss) * HD + d] =
                (bf16)((acc[mi][ni][i] + bv) * scale);
          }
        }
    } else {
      // V^T scatter (proven: WRITE_SIZE stays ideal, L2 absorbs)
#pragma unroll
      for (int mi = 0; mi < 8; ++mi)
#pragma unroll
        for (int ni = 0; ni < NF; ++ni) {
          int gcol = n0 + wc * WN + ni * 16 + l15;
          float bv = bias[gcol];
          int e = gcol & 1023, h = e >> 6, d = e & 63;
#pragma unroll
          for (int i = 0; i < 4; ++i) {
            int grow = m0 + mi * 16 + quad * 4 + i;
            int b = grow >> 11, ss = grow & 2047;
            v[(((long)b * NH + h) * HD + d) * SEQ + ss] =
                (bf16)(acc[mi][ni][i] + bv);
          }
        }
    }
  }
#undef LDSA
#undef LDSB
#undef ISSUE64
#undef RD_A
#undef RD_B
#undef MFMAH
}

// ---------------- flash attention: in-register softmax (R12, unchanged) ----
// 1D grid 512 blocks; block 256 = 4 waves x 32 q-rows = 128-row strip.
// Swapped QK^T (A=K, B=Q) + key<->row map: lane holds S[q=m*16+l15][keys
// quad*8+0..7 (+32kk)] = exactly the swapped-PV B-fragment. P stays in
// registers; LDS holds only K and V tiles (16KB).
__global__ __launch_bounds__(256, 2) void attn(
    const bf16* __restrict__ Q, const bf16* __restrict__ K,
    const bf16* __restrict__ Vt, bf16* __restrict__ Y)
{
  __shared__ __align__(16) bf16 Kl[64 * 64];        // 8 KB
  __shared__ __align__(16) bf16 Vl[64 * 64];        // 8 KB
  int L = blockIdx.x;
  int a = L >> 3;
  int hd = (L & 7) + 8 * (a & 7);
  int st = a >> 3;
  int b = hd >> 4, h = hd & 15;
  const bf16* Qp  = Q  + (((long)b * NH + h) * SEQ) * HD;
  const bf16* Kp  = K  + (((long)b * NH + h) * SEQ) * HD;
  const bf16* Vtp = Vt + (((long)b * NH + h) * HD) * SEQ;
  int t = threadIdx.x, wave = t >> 6, lane = t & 63;
  int l15 = lane & 15, quad = lane >> 4;
  // K-frag row map base (per f): key(r=l15, f) = 32*(f>>1)+(l15>>2)*8+(f&1)*4+(l15&3)
  int rkbase = ((l15 >> 2) << 3) + (l15 & 3);

#pragma unroll 1
  for (int pass = 0; pass < 2; ++pass) {
    int q0 = (pass == 0) ? st * 128 : (SEQ - 128) - st * 128;
    int wq0 = q0 + wave * 32;

    // Q fragments (B-operand now): b[j] = Q[q=wq0+m*16+l15][d=quad*8+j+32kd]
    bf16x8 qf[2][2];
#pragma unroll
    for (int m = 0; m < 2; ++m) {
      const bf16* qrow = Qp + (long)(wq0 + m * 16 + l15) * HD + quad * 8;
      qf[m][0] = *(const bf16x8*)(qrow);
      qf[m][1] = *(const bf16x8*)(qrow + 32);
    }
    float lrow[2] = {};
    f32x4 oacc[2][4] = {};

    int ntiles = q0 / 64 + 2;     // block's 128 rows need tiles through q0+127
#pragma unroll 1
    for (int kt = 0; kt < ntiles; ++kt) {
      int k0 = kt * 64;
      __syncthreads();
      // stage K [key][d], V^T [d][key]: unit row*8+u holds chunk u^(row&7)
#pragma unroll
      for (int it = 0; it < 2; ++it) {
        int cu = it * 256 + t;
        int row = cu >> 3, u = cu & 7;
        ld_lds16(&Kp[(long)(k0 + row) * HD + ((u ^ (row & 7)) * 8)],
                 &Kl[(it * 256 + wave * 64) * 8]);
        ld_lds16(&Vtp[(long)row * SEQ + k0 + ((u ^ (row & 7)) * 8)],
                 &Vl[(it * 256 + wave * 64) * 8]);
      }
      __syncthreads();
      if (k0 > wq0 + 31) continue;   // wave's rows all masked for this tile

      // swapped QK: sc[m][f][i] = S[key=k0+32*(f>>1)+quad*8+(f&1)*4+i][q=wq0+m*16+l15]
      f32x4 sc[2][4] = {};
#pragma unroll
      for (int kd = 0; kd < 2; ++kd) {
#pragma unroll
        for (int f = 0; f < 4; ++f) {
          int rk = ((f >> 1) << 5) + ((f & 1) << 2) + rkbase;
          bf16x8 kf = *(const bf16x8*)(&Kl[rk * 64 + (((kd * 4 + quad) ^ (rk & 7)) * 8)]);
          sc[0][f] = __builtin_amdgcn_mfma_f32_16x16x32_bf16(kf, qf[0][kd], sc[0][f], 0, 0, 0);
          sc[1][f] = __builtin_amdgcn_mfma_f32_16x16x32_bf16(kf, qf[1][kd], sc[1][f], 0, 0, 0);
        }
      }

      bool full = (k0 + 63 <= wq0);   // wave-uniform (min row = wq0)
      bf16x8 pb[2][2];                // PV B-frags: pb[m][kk]
#pragma unroll
      for (int m = 0; m < 2; ++m) {
        int qr = wq0 + m * 16 + l15;
#pragma unroll
        for (int f = 0; f < 4; ++f) {
          int kgb = k0 + ((f >> 1) << 5) + quad * 8 + ((f & 1) << 2);
          float e[4];
#pragma unroll
          for (int i = 0; i < 4; ++i) {
            float x = sc[m][f][i];
            if (!full) x = (kgb + i <= qr) ? x : -1e30f;
            e[i] = __builtin_amdgcn_exp2f(x);
          }
          lrow[m] += (e[0] + e[1]) + (e[2] + e[3]);
#pragma unroll
          for (int i = 0; i < 4; ++i)
            pb[m][f >> 1][((f & 1) << 2) + i] = (bf16)e[i];
        }
      }

      // swapped PV: oacc[m][ni][i] = O[q=wq0+m*16+l15][d=ni*16+quad*4+i]
#pragma unroll
      for (int kp = 0; kp < 2; ++kp) {
#pragma unroll
        for (int ni = 0; ni < 4; ++ni) {
          int dd = ni * 16 + l15;
          bf16x8 vf = *(const bf16x8*)(&Vl[dd * 64 + (((kp * 4 + quad) ^ (dd & 7)) * 8)]);
          oacc[0][ni] = __builtin_amdgcn_mfma_f32_16x16x32_bf16(vf, pb[0][kp], oacc[0][ni], 0, 0, 0);
          oacc[1][ni] = __builtin_amdgcn_mfma_f32_16x16x32_bf16(vf, pb[1][kp], oacc[1][ni], 0, 0, 0);
        }
      }
    }
    // epilogue: row-sum over the 4 quads (lanes +-16, +-32), write Y bf16
#pragma unroll
    for (int m = 0; m < 2; ++m) {
      float rs = lrow[m];
      rs += __shfl_xor(rs, 16);
      rs += __shfl_xor(rs, 32);
      float inv = 1.0f / rs;
      int qr = wq0 + m * 16 + l15;
      bf16* dst = Y + ((long)(b * SEQ + qr)) * EMB + h * HD + quad * 4;
#pragma unroll
      for (int ni = 0; ni < 4; ++ni) {
        bf16x4 o;
#pragma unroll
        for (int i = 0; i < 4; ++i) o[i] = (bf16)(oacc[m][ni][i] * inv);
        *(bf16x4*)(&dst[ni * 16]) = o;
      }
    }
  }
}

extern "C" void kernel_launch(void* const* d_in, const int* in_sizes, int n_in,
                              void* d_out, int out_size, void* d_ws, size_t ws_size,
                              hipStream_t stream) {
  const float* x      = (const float*)d_in[0];
  const float* W_attn = (const float*)d_in[1];
  const float* b_attn = (const float*)d_in[2];
  const float* W_proj = (const float*)d_in[3];
  const float* b_proj = (const float*)d_in[4];
  float* out = (float*)d_out;
  char* ws = (char*)d_ws;
  bf16* xb  = (bf16*)(ws);                 // 16.78 MB
  bf16* WaT = (bf16*)(ws + 16777216);      //  6.29 MB
  bf16* WpT = (bf16*)(ws + 23068672);      //  2.10 MB
  bf16* Qb  = (bf16*)(ws + 25165824);      // 16.78 MB (pre-scaled)
  bf16* Kb  = (bf16*)(ws + 41943040);      // 16.78 MB
  bf16* Vtb = (bf16*)(ws + 58720256);      // 16.78 MB (transposed [b,h,d,s])
  bf16* Yb  = (bf16*)(ws + 75497472);      // 16.78 MB

  prep<<<12288, 256, 0, stream>>>(x, xb, BATCH * SEQ * EMB,
                                  W_attn, W_proj, WaT, WpT);
  gemm_cv<4, 0><<<768, 256, 0, stream>>>(xb, WaT, b_attn, Qb, Kb, Vtb, nullptr);
  attn<<<512, 256, 0, stream>>>(Qb, Kb, Vtb, Yb);
  gemm_cv<2, 1><<<512, 256, 0, stream>>>(Yb, WpT, b_proj,
                                         nullptr, nullptr, nullptr, out);
}